// Round 2
// baseline (13011.710 us; speedup 1.0000x reference)
//
#include <hip/hip_runtime.h>

// RNN scan on MI355X — round 2.
// k1: xw[t][b][:] = bf16(x[b,t,:] @ W_x) + b_x + b_h  (t-major, bf16)
// k2: persistent scan, 4 clusters (16 batch rows) x 2 members (256 cols each).
//     W_h half register-resident (256 VGPR B-frags/lane). Own h half lives in
//     LDS (ping-pong); only the other 256 cols cross WGs, via agent-scope
//     relaxed atomics (sc0 sc1, no buffer_wbl2/buffer_inv fences). Flags are
//     per-member monotonic step counters; __syncthreads() vmcnt-drain before
//     the flag store provides release ordering.
// k3: out[b] = h_T[b,:] @ W_fc + b_fc.

#define T_STEPS 1024
#define HID     512
#define LROW    264            // LDS row stride in ushorts (256 + 8 pad -> 2-way banks)
#define HSLAB   (64 * 512)     // ushorts per h slab

typedef __attribute__((ext_vector_type(8))) short  short8;   // 8 bf16 (MFMA A/B frag)
typedef __attribute__((ext_vector_type(4))) float  f32x4;    // MFMA C/D frag

typedef unsigned short ushort_t;
typedef unsigned int   uint_t;

__device__ __forceinline__ ushort_t f2bf(float f) {
    union { float f; uint_t u; } c; c.f = f;
    uint_t u = c.u;
    return (ushort_t)((u + 0x7fffu + ((u >> 16) & 1u)) >> 16);   // RNE
}
__device__ __forceinline__ float bf2f(ushort_t h) {
    union { uint_t u; float f; } c; c.u = ((uint_t)h) << 16;
    return c.f;
}
__device__ __forceinline__ float tanh_fast(float x) {
    float ax = __builtin_fabsf(x);
    float t  = __expf(-2.0f * ax);          // v_exp_f32 path
    float r  = (1.0f - t) / (1.0f + t);     // <= 1 always
    return x < 0.0f ? -r : r;
}

// ---------------------------------------------------------------------------
// k1: xw = x @ W_x + (b_x + b_h).  64x64 tile per WG (one t, all 64 b), BK=32.
// ---------------------------------------------------------------------------
__global__ __launch_bounds__(256) void k1_xproj(
    const float* __restrict__ x, const float* __restrict__ Wx,
    const float* __restrict__ bx, const float* __restrict__ bh,
    ushort_t* __restrict__ xw)
{
    __shared__ __align__(16) ushort_t Al[64 * 32];
    __shared__ __align__(16) ushort_t Bl[64 * 32];

    const int t0   = blockIdx.y;
    const int n0   = blockIdx.x * 64;
    const int tid  = threadIdx.x;
    const int wave = tid >> 6;
    const int lane = tid & 63;
    const int lm   = lane & 15;
    const int quad = lane >> 4;

    f32x4 acc[4];
    #pragma unroll
    for (int i = 0; i < 4; ++i) acc[i] = (f32x4){0.f, 0.f, 0.f, 0.f};

    const int ar = tid >> 2, ac = (tid & 3) * 8;
    const int bk = tid >> 3, bc = (tid & 7) * 8;

    for (int kb = 0; kb < 16; ++kb) {
        {
            const float* ap = x + ((size_t)ar * T_STEPS + t0) * HID + kb * 32 + ac;
            short8 pack;
            #pragma unroll
            for (int i = 0; i < 8; ++i) pack[i] = (short)f2bf(ap[i]);
            *(short8*)&Al[ar * 32 + ac] = pack;
        }
        {
            const float* bp = Wx + (size_t)(kb * 32 + bk) * HID + n0 + bc;
            #pragma unroll
            for (int i = 0; i < 8; ++i) Bl[(bc + i) * 32 + bk] = f2bf(bp[i]);
        }
        __syncthreads();
        short8 bfr = *(const short8*)&Bl[(wave * 16 + lm) * 32 + quad * 8];
        #pragma unroll
        for (int mf = 0; mf < 4; ++mf) {
            short8 afr = *(const short8*)&Al[(mf * 16 + lm) * 32 + quad * 8];
            acc[mf] = __builtin_amdgcn_mfma_f32_16x16x32_bf16(afr, bfr, acc[mf], 0, 0, 0);
        }
        __syncthreads();
    }

    const int n = n0 + wave * 16 + lm;
    const float bias = bx[n] + bh[n];
    #pragma unroll
    for (int mf = 0; mf < 4; ++mf)
        #pragma unroll
        for (int r = 0; r < 4; ++r) {
            int b = mf * 16 + quad * 4 + r;
            xw[((size_t)t0 * 64 + b) * HID + n] = f2bf(acc[mf][r] + bias);
        }
}

// ---------------------------------------------------------------------------
// k2: persistent scan. grid=8: cluster = blockIdx>>1 (16 rows), member =
// blockIdx&1 (256 cols). Wave owns 64 cols (4 ntiles); B-frags wf[4][16] in
// VGPRs. Step: poll other flag -> issue other-half A loads (IF, sc0sc1) ->
// own-half MFMAs from LDS -> other-half MFMAs -> tanh -> LDS(next) + global
// own-half store -> barrier (vmcnt drain) -> flag=t+1.
// ---------------------------------------------------------------------------
__global__ __launch_bounds__(256, 1) void k2_scan(
    const ushort_t* __restrict__ xw, const float* __restrict__ Wh,
    ushort_t* __restrict__ hg, uint_t* __restrict__ flags)
{
    const int cluster = blockIdx.x >> 1;
    const int member  = blockIdx.x & 1;
    const int tid  = threadIdx.x;
    const int wave = tid >> 6;
    const int lane = tid & 63;
    const int lm   = lane & 15;
    const int quad = lane >> 4;
    const int rowbase = cluster * 16;
    const int colbase = member * 256 + wave * 64;      // global col of this wave's nt=0

    __shared__ __align__(16) ushort_t hl[2][16 * LROW];

    // h_0 = 0 in LDS
    for (int i = tid; i < 2 * 16 * LROW; i += 256) ((ushort_t*)hl)[i] = 0;

    // W_h B-frags: wf[nt][kt], B[k][n], n = colbase+nt*16+lm, k = kt*32+quad*8+j
    short8 wf[4][16];
    #pragma unroll
    for (int nt = 0; nt < 4; ++nt) {
        const int n = colbase + nt * 16 + lm;
        #pragma unroll
        for (int kt = 0; kt < 16; ++kt) {
            short8 w;
            #pragma unroll
            for (int j = 0; j < 8; ++j)
                w[j] = (short)f2bf(Wh[(size_t)(kt * 32 + quad * 8 + j) * HID + n]);
            wf[nt][kt] = w;
        }
    }
    __syncthreads();

    uint_t* oflag = flags + (cluster * 2 + (1 - member)) * 16;
    uint_t* mflag = flags + (cluster * 2 + member) * 16;

    // xw prefetch for t=0
    ushort_t xwv[4][4];
    #pragma unroll
    for (int nt = 0; nt < 4; ++nt)
        #pragma unroll
        for (int r = 0; r < 4; ++r)
            xwv[nt][r] = xw[(size_t)(rowbase + quad * 4 + r) * HID + colbase + nt * 16 + lm];

    const int myk0 = 8 * member;        // own-half kt base (k = col of h)
    const int okt0 = 8 * (1 - member);  // other-half kt base

    for (int t = 0; t < T_STEPS; ++t) {
        if (t) {
            while (__hip_atomic_load(oflag, __ATOMIC_RELAXED, __HIP_MEMORY_SCOPE_AGENT)
                   < (uint_t)t)
                __builtin_amdgcn_s_sleep(1);
        }

        // other-half A-frags straight from IF (sc0 sc1, bypass L1/L2)
        const ushort_t* hsrc = hg + (size_t)(t & 1) * HSLAB + (size_t)(rowbase + lm) * HID;
        uint_t od[8][4];
        #pragma unroll
        for (int kk = 0; kk < 8; ++kk) {
            uint_t* p = (uint_t*)(hsrc + (okt0 + kk) * 32 + quad * 8);
            #pragma unroll
            for (int d = 0; d < 4; ++d)
                od[kk][d] = __hip_atomic_load(p + d, __ATOMIC_RELAXED,
                                              __HIP_MEMORY_SCOPE_AGENT);
        }

        // acc init = xw_t (prefetched), then prefetch xw_{t+1}
        f32x4 acc[4];
        #pragma unroll
        for (int nt = 0; nt < 4; ++nt)
            #pragma unroll
            for (int r = 0; r < 4; ++r) acc[nt][r] = bf2f(xwv[nt][r]);
        if (t + 1 < T_STEPS) {
            #pragma unroll
            for (int nt = 0; nt < 4; ++nt)
                #pragma unroll
                for (int r = 0; r < 4; ++r)
                    xwv[nt][r] = xw[((size_t)(t + 1) * 64 + rowbase + quad * 4 + r) * HID
                                    + colbase + nt * 16 + lm];
        }

        // own-half MFMAs from LDS (k in [256*member, 256*member+256))
        const ushort_t* cur = hl[t & 1];
        #pragma unroll
        for (int kk = 0; kk < 8; ++kk) {
            short8 a = *(const short8*)&cur[lm * LROW + kk * 32 + quad * 8];
            #pragma unroll
            for (int nt = 0; nt < 4; ++nt)
                acc[nt] = __builtin_amdgcn_mfma_f32_16x16x32_bf16(
                    a, wf[nt][myk0 + kk], acc[nt], 0, 0, 0);
        }
        // other-half MFMAs from IF loads
        #pragma unroll
        for (int kk = 0; kk < 8; ++kk) {
            union { uint_t u[4]; short8 v; } pk;
            #pragma unroll
            for (int d = 0; d < 4; ++d) pk.u[d] = od[kk][d];
            #pragma unroll
            for (int nt = 0; nt < 4; ++nt)
                acc[nt] = __builtin_amdgcn_mfma_f32_16x16x32_bf16(
                    pk.v, wf[nt][okt0 + kk], acc[nt], 0, 0, 0);
        }

        // tanh -> LDS(next) + agent-scope store of own half
        ushort_t* nxt  = (ushort_t*)hl[(t + 1) & 1];
        ushort_t* hdst = hg + (size_t)((t + 1) & 1) * HSLAB;
        #pragma unroll
        for (int nt = 0; nt < 4; ++nt)
            #pragma unroll
            for (int r = 0; r < 4; ++r) {
                ushort_t hv = f2bf(tanh_fast(acc[nt][r]));
                const int lcol = wave * 64 + nt * 16 + lm;       // member-local col
                nxt[(quad * 4 + r) * LROW + lcol] = hv;
                __hip_atomic_store(
                    hdst + (size_t)(rowbase + quad * 4 + r) * HID + member * 256 + lcol,
                    hv, __ATOMIC_RELAXED, __HIP_MEMORY_SCOPE_AGENT);
            }

        __syncthreads();   // vmcnt(0)+lgkmcnt(0) drain: release for the flag below
        if (tid == 0)
            __hip_atomic_store(mflag, (uint_t)(t + 1), __ATOMIC_RELAXED,
                               __HIP_MEMORY_SCOPE_AGENT);
    }
}

// ---------------------------------------------------------------------------
// k3: out[b] = h_T[b,:] @ W_fc + b_fc.
// ---------------------------------------------------------------------------
__global__ __launch_bounds__(64) void k3_out(
    const ushort_t* __restrict__ hfin, const float* __restrict__ Wfc,
    const float* __restrict__ bfc, float* __restrict__ out)
{
    const int b = blockIdx.x, lane = threadIdx.x;
    float s = 0.f;
    #pragma unroll
    for (int i = 0; i < 8; ++i) {
        int j = i * 64 + lane;
        s += bf2f(hfin[b * HID + j]) * Wfc[j];
    }
    #pragma unroll
    for (int off = 32; off; off >>= 1) s += __shfl_down(s, off, 64);
    if (lane == 0) out[b] = s + bfc[0];
}

// ---------------------------------------------------------------------------
extern "C" void kernel_launch(void* const* d_in, const int* in_sizes, int n_in,
                              void* d_out, int out_size, void* d_ws, size_t ws_size,
                              hipStream_t stream)
{
    const float* x   = (const float*)d_in[0];
    const float* Wx  = (const float*)d_in[1];
    const float* bx  = (const float*)d_in[2];
    const float* Wh  = (const float*)d_in[3];
    const float* bh  = (const float*)d_in[4];
    const float* Wfc = (const float*)d_in[5];
    const float* bfc = (const float*)d_in[6];
    float* out = (float*)d_out;

    char* ws = (char*)d_ws;
    // ws layout:
    //   [0, 67108864)               xw bf16 [1024][64][512]
    //   [67108864, +131072)         hg bf16 [2 slabs][64][512]
    //   [67239936, +512)            flags (8 x 64B-spaced u32)
    ushort_t* xw    = (ushort_t*)ws;
    ushort_t* hg    = (ushort_t*)(ws + 67108864);
    uint_t*   flags = (uint_t*)(ws + 67108864 + 131072);

    // h_0 = 0 (both slabs) + flags = 0, every launch (ws is re-poisoned)
    hipMemsetAsync(ws + 67108864, 0, 131072 + 512, stream);

    k1_xproj<<<dim3(8, 1024), 256, 0, stream>>>(x, Wx, bx, bh, xw);
    k2_scan <<<dim3(8),       256, 0, stream>>>(xw, Wh, hg, flags);
    k3_out  <<<dim3(64),       64, 0, stream>>>(hg, Wfc, bfc, out);
}

// Round 3
// 5019.989 us; speedup vs baseline: 2.5920x; 2.5920x over previous
//
#include <hip/hip_runtime.h>

// RNN scan on MI355X — round 3: fully WG-local recurrence.
// k1: xw[t][n][b] = bf16(x[b,t,:] @ W_x + b_x + b_h)   (k2-native layout)
// k2: grid=4, each WG owns 16 batch rows x all 512 cols. W_h split:
//     k in [0,384): VGPR B-frags wf[8][12] (384 VGPRs/lane, compile-time
//     indexed). k in [384,512): LDS, B-frag-linear (128 KB, conflict-free).
//     h tile in LDS (A-frag order, stride-40 pad), updated in place with two
//     s_barriers/step. No inter-WG communication of any kind. FC epilogue fused.

#define T_STEPS 1024
#define HID     512

typedef __attribute__((ext_vector_type(8))) short  short8;   // 8 bf16 (MFMA A/B frag)
typedef __attribute__((ext_vector_type(4))) short  short4_t; // 4 bf16 (8 B)
typedef __attribute__((ext_vector_type(4))) float  f32x4;    // MFMA C/D frag

typedef unsigned short ushort_t;
typedef unsigned int   uint_t;

__device__ __forceinline__ ushort_t f2bf(float f) {
    union { float f; uint_t u; } c; c.f = f;
    uint_t u = c.u;
    return (ushort_t)((u + 0x7fffu + ((u >> 16) & 1u)) >> 16);   // RNE
}
__device__ __forceinline__ float bf2f(ushort_t h) {
    union { uint_t u; float f; } c; c.u = ((uint_t)h) << 16;
    return c.f;
}
// tanh(x) = 1 - 2/(e^{2x}+1); exp2-based, saturates correctly at +/-1.
__device__ __forceinline__ float tanh_fast(float x) {
    float t = __builtin_amdgcn_exp2f(x * 2.88539008f);   // e^{2x}
    return 1.0f - 2.0f * __builtin_amdgcn_rcpf(t + 1.0f);
}

// ---------------------------------------------------------------------------
// k1: xw = x @ W_x + (b_x + b_h).  64x64 tile per WG (one t, all 64 b), BK=32.
// Output layout: xw[t][n][b] (b fastest, 64 per n) for k2's b64 loads.
// ---------------------------------------------------------------------------
__global__ __launch_bounds__(256) void k1_xproj(
    const float* __restrict__ x, const float* __restrict__ Wx,
    const float* __restrict__ bx, const float* __restrict__ bh,
    ushort_t* __restrict__ xw)
{
    __shared__ __align__(16) ushort_t Al[64 * 32];
    __shared__ __align__(16) ushort_t Bl[64 * 32];

    const int t0   = blockIdx.y;
    const int n0   = blockIdx.x * 64;
    const int tid  = threadIdx.x;
    const int wave = tid >> 6;
    const int lane = tid & 63;
    const int lm   = lane & 15;
    const int quad = lane >> 4;

    f32x4 acc[4];
    #pragma unroll
    for (int i = 0; i < 4; ++i) acc[i] = (f32x4){0.f, 0.f, 0.f, 0.f};

    const int ar = tid >> 2, ac = (tid & 3) * 8;
    const int bk = tid >> 3, bc = (tid & 7) * 8;

    for (int kb = 0; kb < 16; ++kb) {
        {
            const float* ap = x + ((size_t)ar * T_STEPS + t0) * HID + kb * 32 + ac;
            short8 pack;
            #pragma unroll
            for (int i = 0; i < 8; ++i) pack[i] = (short)f2bf(ap[i]);
            *(short8*)&Al[ar * 32 + ac] = pack;
        }
        {
            const float* bp = Wx + (size_t)(kb * 32 + bk) * HID + n0 + bc;
            #pragma unroll
            for (int i = 0; i < 8; ++i) Bl[(bc + i) * 32 + bk] = f2bf(bp[i]);
        }
        __syncthreads();
        short8 bfr = *(const short8*)&Bl[(wave * 16 + lm) * 32 + quad * 8];
        #pragma unroll
        for (int mf = 0; mf < 4; ++mf) {
            short8 afr = *(const short8*)&Al[(mf * 16 + lm) * 32 + quad * 8];
            acc[mf] = __builtin_amdgcn_mfma_f32_16x16x32_bf16(afr, bfr, acc[mf], 0, 0, 0);
        }
        __syncthreads();
    }

    // D layout: n = lane&15 (+wave*16), b = quad*4 + r (+mf*16)
    const int n = n0 + wave * 16 + lm;
    const float bias = bx[n] + bh[n];
    #pragma unroll
    for (int mf = 0; mf < 4; ++mf) {
        short4_t pk;
        #pragma unroll
        for (int r = 0; r < 4; ++r) pk[r] = (short)f2bf(acc[mf][r] + bias);
        *(short4_t*)&xw[((size_t)t0 * HID + n) * 64 + mf * 16 + quad * 4] = pk;
    }
}

// ---------------------------------------------------------------------------
// k2: grid=4 x 256 threads. WG owns rows [16*blockIdx, +16).
// LDS (ushort):
//   Wl [4 ktp][32 ntg][64 lane][8]  = 65536 ush (128 KB)  W_h k in [384,512)
//   hA [16 kt][16 m][40]            = 10240 ush (20 KB)   h tile, A-frag order
// ---------------------------------------------------------------------------
__global__ __launch_bounds__(256, 1) void k2_scan(
    const ushort_t* __restrict__ xw, const float* __restrict__ Wh,
    const float* __restrict__ Wfc, const float* __restrict__ bfc,
    float* __restrict__ out)
{
    __shared__ __align__(16) ushort_t lds[75776];
    ushort_t* Wl = lds;            // 65536 ush
    ushort_t* hA = lds + 65536;    // 10240 ush

    const int tid  = threadIdx.x;
    const int wave = tid >> 6;
    const int lane = tid & 63;
    const int lm   = lane & 15;
    const int quad = lane >> 4;
    const int rowbase = blockIdx.x * 16;
    const int colb    = wave * 128;      // this wave's first output column

    // h_0 = 0
    for (int i = tid; i < 10240; i += 256) hA[i] = 0;

    // Wl init: chunk c = (ktp*32 + ntg)*64 + l holds B-frag bytes for
    // n = ntg*16 + (l&15), k = 384 + ktp*32 + (l>>4)*8 + j
    for (int i = 0; i < 32; ++i) {
        int c   = i * 256 + tid;
        int l   = c & 63;
        int ntg = (c >> 6) & 31;
        int ktp = c >> 11;
        int n   = ntg * 16 + (l & 15);
        int kb  = 384 + ktp * 32 + (l >> 4) * 8;
        short8 w;
        #pragma unroll
        for (int j = 0; j < 8; ++j) w[j] = (short)f2bf(Wh[(size_t)(kb + j) * HID + n]);
        *(short8*)&Wl[(size_t)c * 8] = w;
    }

    // wf[nt][kt]: W_h k in [0,384), n = colb + nt*16 + lm, k = kt*32+quad*8+j
    // ALL register indices compile-time (the round-2 spill fix).
    short8 wf[8][12];
    #pragma unroll
    for (int nt = 0; nt < 8; ++nt) {
        const int n = colb + nt * 16 + lm;
        #pragma unroll
        for (int kt = 0; kt < 12; ++kt) {
            short8 w;
            #pragma unroll
            for (int j = 0; j < 8; ++j)
                w[j] = (short)f2bf(Wh[(size_t)(kt * 32 + quad * 8 + j) * HID + n]);
            wf[nt][kt] = w;
        }
    }
    __syncthreads();

    for (int t = 0; t < T_STEPS; ++t) {
        // xw loads (needed only after the MFMAs -> latency fully hidden)
        short4_t xv[8];
        #pragma unroll
        for (int nt = 0; nt < 8; ++nt)
            xv[nt] = *(const short4_t*)&xw[((size_t)t * HID + colb + nt * 16 + lm) * 64
                                           + rowbase + quad * 4];

        f32x4 acc[8];
        #pragma unroll
        for (int nt = 0; nt < 8; ++nt) acc[nt] = (f32x4){0.f, 0.f, 0.f, 0.f};

        // k in [0,384): B from VGPRs
        #pragma unroll
        for (int kt = 0; kt < 12; ++kt) {
            short8 a = *(const short8*)&hA[kt * 640 + lm * 40 + quad * 8];
            #pragma unroll
            for (int nt = 0; nt < 8; ++nt)
                acc[nt] = __builtin_amdgcn_mfma_f32_16x16x32_bf16(a, wf[nt][kt], acc[nt], 0, 0, 0);
        }
        // k in [384,512): B from LDS (conflict-free b128: 64 lanes x consecutive 16B)
        #pragma unroll
        for (int ktp = 0; ktp < 4; ++ktp) {
            short8 a = *(const short8*)&hA[(12 + ktp) * 640 + lm * 40 + quad * 8];
            #pragma unroll
            for (int nt = 0; nt < 8; ++nt) {
                short8 b = *(const short8*)&Wl[(size_t)((ktp * 32 + (colb >> 4) + nt) * 64 + lane) * 8];
                acc[nt] = __builtin_amdgcn_mfma_f32_16x16x32_bf16(a, b, acc[nt], 0, 0, 0);
            }
        }

        __syncthreads();   // all hA reads for step t complete

        // h_{t+1} = tanh(acc + xw): D layout n-col = lm(+nt*16+colb), m = quad*4+r
        #pragma unroll
        for (int nt = 0; nt < 8; ++nt) {
            const int c = colb + nt * 16 + lm;
            #pragma unroll
            for (int r = 0; r < 4; ++r) {
                float s = acc[nt][r] + bf2f((ushort_t)xv[nt][r]);
                hA[(c >> 5) * 640 + (quad * 4 + r) * 40 + (c & 31)] = f2bf(tanh_fast(s));
            }
        }

        __syncthreads();   // h_{t+1} visible to all waves
    }

    // fused FC epilogue: out[rowbase+m] = h_T[m,:] . W_fc + b_fc
    #pragma unroll
    for (int r2 = 0; r2 < 4; ++r2) {
        const int m = wave * 4 + r2;
        float s = 0.f;
        #pragma unroll
        for (int i = 0; i < 8; ++i) {
            int k = i * 64 + lane;
            s += bf2f(hA[(k >> 5) * 640 + m * 40 + (k & 31)]) * Wfc[k];
        }
        #pragma unroll
        for (int off = 32; off; off >>= 1) s += __shfl_down(s, off, 64);
        if (lane == 0) out[rowbase + m] = s + bfc[0];
    }
}

// ---------------------------------------------------------------------------
extern "C" void kernel_launch(void* const* d_in, const int* in_sizes, int n_in,
                              void* d_out, int out_size, void* d_ws, size_t ws_size,
                              hipStream_t stream)
{
    const float* x   = (const float*)d_in[0];
    const float* Wx  = (const float*)d_in[1];
    const float* bx  = (const float*)d_in[2];
    const float* Wh  = (const float*)d_in[3];
    const float* bh  = (const float*)d_in[4];
    const float* Wfc = (const float*)d_in[5];
    const float* bfc = (const float*)d_in[6];
    float* out = (float*)d_out;

    // ws: xw bf16 [1024][512 n][64 b] = 64 Mi ush = 128 MB? no: 1024*512*64*2B = 64 MiB
    ushort_t* xw = (ushort_t*)d_ws;

    k1_xproj<<<dim3(8, 1024), 256, 0, stream>>>(x, Wx, bx, bh, xw);
    k2_scan <<<dim3(4),       256, 0, stream>>>(xw, Wh, Wfc, bfc, out);
}

// Round 4
// 2602.911 us; speedup vs baseline: 4.9989x; 1.9286x over previous
//
#include <hip/hip_runtime.h>

// RNN scan on MI355X — round 4: transposed MFMA (A = W_h, B = h) so the
// h-store is packed b64 into a fragment-linear hT that the next step reads
// conflict-free. 8 waves/WG (2/SIMD) for latency hiding.
// k1: xw[t][b][n] = bf16(x[b,t,:] @ W_x + b_x + b_h)   (transposed MFMA too)
// k2: grid=4, WG owns 16 batch rows x all 512 cols. W_h k<384 in VGPR A-frags
//     wfA[4][12] (192 VGPR, compile-time indexed); k in [384,512) in LDS
//     (A-frag-linear, 128 KB). hT (16 KB, B-frag-linear) in-place, 2 barriers.
//     FC epilogue fused. No inter-WG traffic.

#define T_STEPS 1024
#define HID     512

typedef __attribute__((ext_vector_type(8))) short  short8;   // 8 bf16 (MFMA A/B frag)
typedef __attribute__((ext_vector_type(4))) short  short4_t; // 4 bf16 (8 B)
typedef __attribute__((ext_vector_type(4))) float  f32x4;    // MFMA C/D frag

typedef unsigned short ushort_t;
typedef unsigned int   uint_t;

__device__ __forceinline__ ushort_t f2bf(float f) {
    union { float f; uint_t u; } c; c.f = f;
    uint_t u = c.u;
    return (ushort_t)((u + 0x7fffu + ((u >> 16) & 1u)) >> 16);   // RNE
}
__device__ __forceinline__ float bf2f(ushort_t h) {
    union { uint_t u; float f; } c; c.u = ((uint_t)h) << 16;
    return c.f;
}
// tanh(x) = 1 - 2/(e^{2x}+1); exp2-based, saturates correctly at +/-1.
__device__ __forceinline__ float tanh_fast(float x) {
    float t = __builtin_amdgcn_exp2f(x * 2.88539008f);   // e^{2x}
    return 1.0f - 2.0f * __builtin_amdgcn_rcpf(t + 1.0f);
}

// ---------------------------------------------------------------------------
// k1: xw[t][b][n] = x @ W_x + (b_x + b_h), transposed MFMA: A = W_x^T
// (m = n), B = x^T (n = b). 64n x 64b tile per WG, BK=32. Stride-40 LDS rows.
// ---------------------------------------------------------------------------
__global__ __launch_bounds__(256) void k1_xproj(
    const float* __restrict__ x, const float* __restrict__ Wx,
    const float* __restrict__ bx, const float* __restrict__ bh,
    ushort_t* __restrict__ xw)
{
    __shared__ __align__(16) ushort_t Wl[64 * 40];   // [n][k] bf16 (A-side)
    __shared__ __align__(16) ushort_t Xl[64 * 40];   // [b][k] bf16 (B-side)

    const int t0   = blockIdx.y;
    const int n0   = blockIdx.x * 64;
    const int tid  = threadIdx.x;
    const int wave = tid >> 6;
    const int lane = tid & 63;
    const int lm   = lane & 15;
    const int quad = lane >> 4;

    f32x4 acc[4];
    #pragma unroll
    for (int i = 0; i < 4; ++i) acc[i] = (f32x4){0.f, 0.f, 0.f, 0.f};

    // bias for this lane's 4 output n's (D rows): n = n0 + wave*16 + quad*4 + r
    float biasv[4];
    #pragma unroll
    for (int r = 0; r < 4; ++r) {
        int n = n0 + wave * 16 + quad * 4 + r;
        biasv[r] = bx[n] + bh[n];
    }

    const int ar = tid >> 2, ac = (tid & 3) * 8;   // X staging: b row, 8 k's
    const int bk = tid >> 3, bc = (tid & 7) * 8;   // W staging: k, 8 n's

    for (int kb = 0; kb < 16; ++kb) {
        { // stage X rows (natural k-contiguous)
            const float* ap = x + ((size_t)ar * T_STEPS + t0) * HID + kb * 32 + ac;
            short8 pack;
            #pragma unroll
            for (int i = 0; i < 8; ++i) pack[i] = (short)f2bf(ap[i]);
            *(short8*)&Xl[ar * 40 + ac] = pack;
        }
        { // stage W_x swizzled: Wl[n][k]
            const float* bp = Wx + (size_t)(kb * 32 + bk) * HID + n0 + bc;
            #pragma unroll
            for (int i = 0; i < 8; ++i) Wl[(bc + i) * 40 + bk] = f2bf(bp[i]);
        }
        __syncthreads();
        short8 afr = *(const short8*)&Wl[(wave * 16 + lm) * 40 + quad * 8];
        #pragma unroll
        for (int bt = 0; bt < 4; ++bt) {
            short8 bfr = *(const short8*)&Xl[(bt * 16 + lm) * 40 + quad * 8];
            acc[bt] = __builtin_amdgcn_mfma_f32_16x16x32_bf16(afr, bfr, acc[bt], 0, 0, 0);
        }
        __syncthreads();
    }

    // D layout: col = b_local = lm (+bt*16), row = n_local = quad*4+r (+wave*16)
    #pragma unroll
    for (int bt = 0; bt < 4; ++bt) {
        short4_t pk;
        #pragma unroll
        for (int r = 0; r < 4; ++r) pk[r] = (short)f2bf(acc[bt][r] + biasv[r]);
        *(short4_t*)&xw[((size_t)t0 * 64 + bt * 16 + lm) * HID
                        + n0 + wave * 16 + quad * 4] = pk;
    }
}

// ---------------------------------------------------------------------------
// k2: grid=4 x 512 threads (8 waves). WG owns b rows [16*blockIdx, +16).
// LDS (ushort):
//   Wl [4 ktp][32 mtg][64 lane][8] = 65536 ush (128 KB)  W_h A-frags, k in [384,512)
//   hT [16 kt][64 lane][8]         =  8192 ush ( 16 KB)  h B-frags, frag-linear
// hT element (b,k): addr = ((k>>5)*64 + ((k>>3)&3)*16 + b)*8 + (k&7)
// ---------------------------------------------------------------------------
__global__ __launch_bounds__(512, 2) void k2_scan(
    const ushort_t* __restrict__ xw, const float* __restrict__ Wh,
    const float* __restrict__ Wfc, const float* __restrict__ bfc,
    float* __restrict__ out)
{
    __shared__ __align__(16) ushort_t lds[73728];
    ushort_t* Wl = lds;            // 65536 ush
    ushort_t* hT = lds + 65536;    //  8192 ush

    const int tid  = threadIdx.x;
    const int wave = tid >> 6;
    const int lane = tid & 63;
    const int lm   = lane & 15;
    const int quad = lane >> 4;
    const int rowbase = blockIdx.x * 16;   // batch rows
    const int colb    = wave * 64;         // this wave's first output column

    // h_0 = 0
    for (int i = tid; i < 8192; i += 512) hT[i] = 0;

    // Wl init: chunk c = (ktp*32 + mtg)*64 + l holds A-frag bytes for
    // m = n = mtg*16 + (l&15), k = (12+ktp)*32 + (l>>4)*8 + j
    for (int i = 0; i < 16; ++i) {
        int c   = i * 512 + tid;
        int l   = c & 63;
        int mtg = (c >> 6) & 31;
        int ktp = c >> 11;
        int n   = mtg * 16 + (l & 15);
        int kb  = (12 + ktp) * 32 + (l >> 4) * 8;
        short8 w;
        #pragma unroll
        for (int j = 0; j < 8; ++j) w[j] = (short)f2bf(Wh[(size_t)(kb + j) * HID + n]);
        *(short8*)&Wl[(size_t)c * 8] = w;
    }

    // wfA[mt][kt]: A[m = colb+mt*16+lm][k = kt*32+quad*8+j], k in [0,384).
    // ALL register indices compile-time.
    short8 wfA[4][12];
    #pragma unroll
    for (int mt = 0; mt < 4; ++mt) {
        const int n = colb + mt * 16 + lm;
        #pragma unroll
        for (int kt = 0; kt < 12; ++kt) {
            short8 w;
            #pragma unroll
            for (int j = 0; j < 8; ++j)
                w[j] = (short)f2bf(Wh[(size_t)(kt * 32 + quad * 8 + j) * HID + n]);
            wfA[mt][kt] = w;
        }
    }
    __syncthreads();

    for (int t = 0; t < T_STEPS; ++t) {
        // xw loads: one b64 per mt (needed only pre-tanh -> latency hidden)
        short4_t xv[4];
        #pragma unroll
        for (int mt = 0; mt < 4; ++mt)
            xv[mt] = *(const short4_t*)&xw[((size_t)t * 64 + rowbase + lm) * HID
                                           + colb + mt * 16 + quad * 4];

        f32x4 acc[4];
        #pragma unroll
        for (int mt = 0; mt < 4; ++mt) acc[mt] = (f32x4){0.f, 0.f, 0.f, 0.f};

        // k in [0,384): A from VGPRs, B (hT) from LDS (conflict-free b128)
        #pragma unroll
        for (int kt = 0; kt < 12; ++kt) {
            short8 b = *(const short8*)&hT[(kt * 64 + lane) * 8];
            #pragma unroll
            for (int mt = 0; mt < 4; ++mt)
                acc[mt] = __builtin_amdgcn_mfma_f32_16x16x32_bf16(wfA[mt][kt], b, acc[mt], 0, 0, 0);
        }
        // k in [384,512): A from LDS
        #pragma unroll
        for (int ktp = 0; ktp < 4; ++ktp) {
            short8 b = *(const short8*)&hT[((12 + ktp) * 64 + lane) * 8];
            #pragma unroll
            for (int mt = 0; mt < 4; ++mt) {
                short8 a = *(const short8*)&Wl[(size_t)((ktp * 32 + wave * 4 + mt) * 64 + lane) * 8];
                acc[mt] = __builtin_amdgcn_mfma_f32_16x16x32_bf16(a, b, acc[mt], 0, 0, 0);
            }
        }

        __syncthreads();   // all hT reads for step t complete

        // h_{t+1}: lane holds (b = lm, n = colb + mt*16 + quad*4 + r).
        // Packed b64 store into frag-linear hT.
        #pragma unroll
        for (int mt = 0; mt < 4; ++mt) {
            short4_t pk;
            #pragma unroll
            for (int r = 0; r < 4; ++r)
                pk[r] = (short)f2bf(tanh_fast(acc[mt][r] + bf2f((ushort_t)xv[mt][r])));
            const int n = colb + mt * 16 + quad * 4;     // n&7 = (quad&1)*4
            *(short4_t*)&hT[(size_t)(((n >> 5) * 64 + ((n >> 3) & 3) * 16 + lm) * 8
                                     + (n & 7))] = pk;
        }

        __syncthreads();   // h_{t+1} visible to all waves
    }

    // fused FC epilogue: out[rowbase+b] = h_T[b,:] . W_fc + b_fc
    // wave handles b = wave*2 + {0,1}; lane sums n = lane*8 .. +8 (one b128)
    #pragma unroll
    for (int bb = 0; bb < 2; ++bb) {
        const int b = wave * 2 + bb;
        short8 hv = *(const short8*)&hT[(((lane >> 2) * 64 + (lane & 3) * 16 + b) * 8)];
        float s = 0.f;
        #pragma unroll
        for (int j = 0; j < 8; ++j) s += bf2f((ushort_t)hv[j]) * Wfc[lane * 8 + j];
        #pragma unroll
        for (int off = 32; off; off >>= 1) s += __shfl_down(s, off, 64);
        if (lane == 0) out[rowbase + b] = s + bfc[0];
    }
}

// ---------------------------------------------------------------------------
extern "C" void kernel_launch(void* const* d_in, const int* in_sizes, int n_in,
                              void* d_out, int out_size, void* d_ws, size_t ws_size,
                              hipStream_t stream)
{
    const float* x   = (const float*)d_in[0];
    const float* Wx  = (const float*)d_in[1];
    const float* bx  = (const float*)d_in[2];
    const float* Wh  = (const float*)d_in[3];
    const float* bh  = (const float*)d_in[4];
    const float* Wfc = (const float*)d_in[5];
    const float* bfc = (const float*)d_in[6];
    float* out = (float*)d_out;

    // ws: xw bf16 [1024 t][64 b][512 n] = 64 MiB
    ushort_t* xw = (ushort_t*)d_ws;

    k1_xproj<<<dim3(8, 1024), 256, 0, stream>>>(x, Wx, bx, bh, xw);
    k2_scan <<<dim3(4),       512, 0, stream>>>(xw, Wh, Wfc, bfc, out);
}